// Round 9
// baseline (51.863 us; speedup 1.0000x reference)
//
#include <hip/hip_runtime.h>
#include <math.h>

#define T_TOTAL   131072
#define POSE_FLTS (131072 * 216)       // 28311552
#define BT        64                   // timesteps per scan unit / block
#define NU        (T_TOTAL / BT)       // 2048 units
#define F4PB      (BT * 54)            // 3456 float4 per unit slice
#define TILE_W    65                   // 64 ts + boundary column
#define TILE_F    72                   // compact floats per ts
#define SCR       (TILE_F * TILE_W)    // 4680 floats = 18720 B
#define FLOOR_YC  (-0.93f)
#define GRAV_Y    (-0.0018f)
#define NEG_INF   (-INFINITY)

typedef float floatx4 __attribute__((ext_vector_type(4)));

// ---------------- small math helpers (constant-indexed after inlining) ------

__device__ __forceinline__ void mat3mul(const float* A, const float* B, float* C) {
#pragma unroll
    for (int r = 0; r < 3; ++r) {
#pragma unroll
        for (int c = 0; c < 3; ++c) {
            C[r * 3 + c] = fmaf(A[r * 3 + 2], B[6 + c],
                           fmaf(A[r * 3 + 1], B[3 + c],
                                A[r * 3 + 0] * B[c]));
        }
    }
}

__device__ __forceinline__ void mva(const float* R, const float* b,
                                    const float* pin, float* pout) {
#pragma unroll
    for (int r = 0; r < 3; ++r) {
        pout[r] = pin[r] + fmaf(R[r * 3 + 2], b[2],
                            fmaf(R[r * 3 + 1], b[1], R[r * 3 + 0] * b[0]));
    }
}

__device__ __forceinline__ float sel_foot(const float f[12], int idx, int c) {
    float r = f[0 + c];
    r = (idx == 1) ? f[3 + c] : r;
    r = (idx == 2) ? f[6 + c] : r;
    r = (idx == 3) ? f[9 + c] : r;
    return r;
}

// FK core on a compact 72-float pose (joint offsets 0,9,18,28,37,51,60)
__device__ __forceinline__ void fk_core(const float* Pl,
                                        const float* __restrict__ bone,
                                        float feet[12], float* fmin) {
    const float* M0 = Pl + 0;
    const float* M1 = Pl + 9;
    const float* M2 = Pl + 18;
    const float* M3 = Pl + 28;
    const float* M4 = Pl + 37;
    const float* M5 = Pl + 51;
    const float* M6 = Pl + 60;

    float R1[9], R2[9], R3[9], R4[9], R5[9], R6[9];
    mat3mul(M0, M1, R1);
    mat3mul(M0, M2, R2);
    mat3mul(R1, M3, R3);
    mat3mul(R2, M4, R4);
    mat3mul(R3, M5, R5);
    mat3mul(R4, M6, R6);

    float p0[3] = {bone[0], bone[1], bone[2]};
    float p1[3], p2[3], p3[3], p4a[3], p5[3], p6[3], p7[3], p8[3];
    mva(M0, bone + 3,  p0, p1);
    mva(M0, bone + 6,  p0, p2);
    mva(R1, bone + 9,  p1, p3);
    mva(R2, bone + 12, p2, p4a);
    mva(R3, bone + 15, p3, p5);
    mva(R4, bone + 18, p4a, p6);
    mva(R5, bone + 21, p5, p7);
    mva(R6, bone + 24, p6, p8);

    // FEET = [7,5,8,6]
    feet[0] = p7[0]; feet[1]  = p7[1]; feet[2]  = p7[2];
    feet[3] = p5[0]; feet[4]  = p5[1]; feet[5]  = p5[2];
    feet[6] = p8[0]; feet[7]  = p8[1]; feet[8]  = p8[2];
    feet[9] = p6[0]; feet[10] = p6[1]; feet[11] = p6[2];
    *fmin = fminf(fminf(p5[1], p6[1]), fminf(p7[1], p8[1]));
}

// FK from transposed compact LDS tile: float f of column c at tile[f*TILE_W+c]
// (stride 65 across lanes -> 2 lanes/bank, conflict-free)
__device__ __forceinline__ void fk_feet_col(const float* __restrict__ tile, int col,
                                            const float* __restrict__ bone,
                                            float feet[12], float* fmin) {
    float Pl[TILE_F];
#pragma unroll
    for (int f = 0; f < TILE_F; ++f) Pl[f] = tile[f * TILE_W + col];
    fk_core(Pl, bone, feet, fmin);
}

// inclusive wave scan (non-commutative compose, earlier = lower lane)
__device__ __forceinline__ void wave_incl_scan(float& Sx, float& Sz,
                                               float& A, float& B, int lane) {
#pragma unroll
    for (int off = 1; off < 64; off <<= 1) {
        float ox = __shfl_up(Sx, off, 64);
        float oz = __shfl_up(Sz, off, 64);
        float oA = __shfl_up(A, off, 64);
        float oB = __shfl_up(B, off, 64);
        if (lane >= off) {
            Sx += ox;
            Sz += oz;
            B = fmaxf(oB + A, B);  // B uses pre-update A
            A = oA + A;
        }
    }
}

// scatter one copied float4 into the transposed compact tile (if needed)
__device__ __forceinline__ void extract_tile(float* __restrict__ tile, int idx, floatx4 q) {
    int tsl = idx / 54;
    int w   = idx - tsl * 54;
    int base = -1;
    if (w <= 6)                  base = 4 * w;       // floats 0..27
    else if (w >= 9 && w <= 13)  base = 4 * w - 8;   // floats 36..55 -> 28..47
    else if (w >= 15 && w <= 20) base = 4 * w - 12;  // floats 60..83 -> 48..71
    if (base >= 0) {
        tile[(base + 0) * TILE_W + tsl] = q.x;
        tile[(base + 1) * TILE_W + tsl] = q.y;
        tile[(base + 2) * TILE_W + tsl] = q.z;
        tile[(base + 3) * TILE_W + tsl] = q.w;
    }
}

// ---------------- main kernel ------------------------------------------------
// Phase A (all 256 threads): load/copy the w<24 region (6 f4 each) + boundary,
// extract to LDS tile, ONE barrier. Then wave0 does FK+scan while waves 1-3
// stream the w in [24,54) region (10 f4 each). No trailing barrier.

__global__ __launch_bounds__(256) void k_main(const float* __restrict__ pose,
                                              const float* __restrict__ bone,
                                              const int* __restrict__ index,
                                              floatx4* __restrict__ outPose4,
                                              float4* __restrict__ vws,
                                              float4* __restrict__ wsAgg) {
    __shared__ __align__(16) float tile[SCR + 4];
    int tid = threadIdx.x, u = blockIdx.x;

    const floatx4* __restrict__ src = (const floatx4*)pose + (size_t)u * F4PB;
    floatx4*       __restrict__ dst = outPose4              + (size_t)u * F4PB;

    // ---- phase A loads: 1536 tile-region f4 (w<24), 6 per thread ----------
    floatx4 a[6];
    int ai[6];
#pragma unroll
    for (int j = 0; j < 6; ++j) {
        int r  = j * 256 + tid;          // 0..1535
        int ts = r / 24;
        int w  = r - ts * 24;            // 0..23
        ai[j]  = ts * 54 + w;
        a[j]   = src[ai[j]];
    }
    floatx4 qb;
    bool hasBnd = (u > 0 && tid >= 128 && tid < 128 + 18);
    if (hasBnd) {
        int k = tid - 128;
        int o = k + (k >= 7 ? 2 : 0) + (k >= 12 ? 1 : 0);   // {0..6,9..13,15..20}
        qb = *(const floatx4*)(pose + ((size_t)u * BT - 1) * 216 + o * 4);
    }

    // ---- drain phase A: NT store + LDS extract ----------------------------
#pragma unroll
    for (int j = 0; j < 6; ++j) {
        __builtin_nontemporal_store(a[j], &dst[ai[j]]);
        extract_tile(tile, ai[j], a[j]);
    }
    if (hasBnd) {
        int k = tid - 128;
#pragma unroll
        for (int i = 0; i < 4; ++i) tile[(4 * k + i) * TILE_W + 64] = qb[i];
    }
    __syncthreads();

    if (tid < 64) {
        // ---- wave 0: FK + velocity + inclusive scan ------------------------
        int lane = tid;
        int t = u * BT + lane;

        float feet[12], fmin;
        fk_feet_col(tile, lane, bone, feet, &fmin);

        float fb[12];
        if (lane == 0 && u > 0) {
            float mb;
            fk_feet_col(tile, 64, bone, fb, &mb);
        }

        float fp[12];
#pragma unroll
        for (int k = 0; k < 12; ++k) fp[k] = __shfl_up(feet[k], 1, 64);
        if (lane == 0 && u > 0) {
#pragma unroll
            for (int k = 0; k < 12; ++k) fp[k] = fb[k];
        }

        float vx, vy, vz;
        if (t == 0) {
            vx = 0.f; vy = GRAV_Y; vz = 0.f;
        } else {
            int idx = index[t];
            vx = sel_foot(fp, idx, 0) - sel_foot(feet, idx, 0);
            vy = GRAV_Y + sel_foot(fp, idx, 1) - sel_foot(feet, idx, 1);
            vz = sel_foot(fp, idx, 2) - sel_foot(feet, idx, 2);
        }
        float ix = vx, iz = vz, iA = vy, iB = FLOOR_YC - fmin;
        wave_incl_scan(ix, iz, iA, iB, lane);

        vws[(size_t)t] = make_float4(ix, iz, iA, iB);   // inclusive state
        if (lane == 63) wsAgg[u] = make_float4(ix, iz, iA, iB);
    } else {
        // ---- waves 1-3: stream the remaining w in [24,54) region ----------
        int tt = tid - 64;               // 0..191
#pragma unroll
        for (int bat = 0; bat < 2; ++bat) {
            floatx4 b[5];
            int bi[5];
#pragma unroll
            for (int j = 0; j < 5; ++j) {
                int r  = (bat * 5 + j) * 192 + tt;   // 0..1919
                int ts = r / 30;
                int w  = 24 + (r - ts * 30);         // 24..53
                bi[j]  = ts * 54 + w;
                b[j]   = src[bi[j]];
            }
#pragma unroll
            for (int j = 0; j < 5; ++j)
                __builtin_nontemporal_store(b[j], &dst[bi[j]]);
        }
    }
}

// ---------------- apply kernel (folds old phase2 + phase3) -------------------
// Every block redundantly scans the 2048 unit aggregates (32 KB from L2),
// extracts the entering state for its 4 units, and applies to 256 elements.

__global__ __launch_bounds__(256) void k_apply(const float4* __restrict__ wsAgg,
                                               const float4* __restrict__ vws,
                                               float* __restrict__ trans) {
    __shared__ float4 wtot[4];
    __shared__ float4 pre[4];
    int tid = threadIdx.x, bk = blockIdx.x;
    int lane = tid & 63, wv = tid >> 6;

    // thread composes aggregates [tid*8, tid*8+8)
    float4 a[8];
#pragma unroll
    for (int k = 0; k < 8; ++k) a[k] = wsAgg[tid * 8 + k];
    float cx = a[0].x, cz = a[0].y, ca = a[0].z, cb = a[0].w;
#pragma unroll
    for (int k = 1; k < 8; ++k) {
        cb = fmaxf(cb + a[k].z, a[k].w);
        ca += a[k].z;
        cx += a[k].x; cz += a[k].y;
    }

    float sx = cx, sz = cz, sa = ca, sb = cb;
    wave_incl_scan(sx, sz, sa, sb, lane);
    if (lane == 63) wtot[wv] = make_float4(sx, sz, sa, sb);

    // lane-exclusive from inclusive
    float ex = __shfl_up(sx, 1, 64);
    float ez = __shfl_up(sz, 1, 64);
    float eA = __shfl_up(sa, 1, 64);
    float eB = __shfl_up(sb, 1, 64);
    if (lane == 0) { ex = 0.f; ez = 0.f; eA = 0.f; eB = NEG_INF; }
    __syncthreads();

    // wave prefix (earlier waves, composed in order)
    float wx = 0.f, wz = 0.f, wA = 0.f, wB = NEG_INF;
    for (int w = 0; w < wv; ++w) {
        float4 c = wtot[w];
        wx += c.x; wz += c.y;
        wB = fmaxf(wB + c.z, c.w);
        wA += c.z;
    }
    float tx = wx + ex, tz = wz + ez;
    float tB = fmaxf(wB + eA, eB);
    float tA = wA + eA;

    // block bk needs entering states for units bk*4 .. bk*4+3; those agg
    // indices live in thread (bk>>1)'s chunk of 8.
    if (tid == (bk >> 1)) {
        int j0 = bk * 4 - tid * 8;       // 0 or 4
        float px = tx, pz = tz, pA = tA, pB = tB;
#pragma unroll
        for (int k = 0; k < 8; ++k) {
            if (k >= j0 && k < j0 + 4)
                pre[k - j0] = make_float4(px, pz, fmaxf(pA, pB), 0.f);
            pB = fmaxf(pB + a[k].z, a[k].w);
            pA += a[k].z;
            px += a[k].x; pz += a[k].y;
        }
    }
    __syncthreads();

    float4 bin = pre[wv];
    size_t t = ((size_t)bk * 4 + wv) * 64 + lane;
    float4 v = vws[t];
    trans[t * 3 + 0] = bin.x + v.x;
    trans[t * 3 + 1] = fmaxf(bin.z + v.z, v.w);
    trans[t * 3 + 2] = bin.y + v.y;
}

// ---------------- launch -----------------------------------------------------

extern "C" void kernel_launch(void* const* d_in, const int* in_sizes, int n_in,
                              void* d_out, int out_size, void* d_ws, size_t ws_size,
                              hipStream_t stream) {
    const float* pose  = (const float*)d_in[0];
    const float* bone  = (const float*)d_in[1];
    const int*   index = (const int*)d_in[2];
    float* out   = (float*)d_out;
    float* trans = out + POSE_FLTS;

    float4* vws   = (float4*)d_ws;         // T entries (2 MB)
    float4* wsAgg = vws + T_TOTAL;         // NU entries
    float4* wsIn  = wsAgg + NU;            // (unused)
    (void)wsIn; (void)ws_size; (void)n_in; (void)in_sizes; (void)out_size;

    k_main <<<NU, 256, 0, stream>>>(pose, bone, index, (floatx4*)out, vws, wsAgg);
    k_apply<<<NU / 4, 256, 0, stream>>>(wsAgg, vws, trans);
}

// Round 10
// 49.728 us; speedup vs baseline: 1.0429x; 1.0429x over previous
//
#include <hip/hip_runtime.h>
#include <math.h>

#define T_TOTAL   131072
#define POSE_FLTS (131072 * 216)       // 28311552
#define BT        64                   // timesteps per scan unit / block
#define NU        (T_TOTAL / BT)       // 2048 units
#define F4PB      (BT * 54)            // 3456 float4 per unit slice
#define TILE_W    65                   // 64 ts + boundary column
#define TILE_F    72                   // compact floats per ts
#define SCR       (TILE_F * TILE_W)    // 4680 floats = 18720 B
#define FLOOR_YC  (-0.93f)
#define GRAV_Y    (-0.0018f)
#define NEG_INF   (-INFINITY)

typedef float floatx4 __attribute__((ext_vector_type(4)));

// ---------------- small math helpers (constant-indexed after inlining) ------

__device__ __forceinline__ void mat3mul(const float* A, const float* B, float* C) {
#pragma unroll
    for (int r = 0; r < 3; ++r) {
#pragma unroll
        for (int c = 0; c < 3; ++c) {
            C[r * 3 + c] = fmaf(A[r * 3 + 2], B[6 + c],
                           fmaf(A[r * 3 + 1], B[3 + c],
                                A[r * 3 + 0] * B[c]));
        }
    }
}

__device__ __forceinline__ void mva(const float* R, const float* b,
                                    const float* pin, float* pout) {
#pragma unroll
    for (int r = 0; r < 3; ++r) {
        pout[r] = pin[r] + fmaf(R[r * 3 + 2], b[2],
                            fmaf(R[r * 3 + 1], b[1], R[r * 3 + 0] * b[0]));
    }
}

__device__ __forceinline__ float sel_foot(const float f[12], int idx, int c) {
    float r = f[0 + c];
    r = (idx == 1) ? f[3 + c] : r;
    r = (idx == 2) ? f[6 + c] : r;
    r = (idx == 3) ? f[9 + c] : r;
    return r;
}

// FK core on a compact 72-float pose (joint offsets 0,9,18,28,37,51,60)
__device__ __forceinline__ void fk_core(const float* Pl,
                                        const float* __restrict__ bone,
                                        float feet[12], float* fmin) {
    const float* M0 = Pl + 0;
    const float* M1 = Pl + 9;
    const float* M2 = Pl + 18;
    const float* M3 = Pl + 28;
    const float* M4 = Pl + 37;
    const float* M5 = Pl + 51;
    const float* M6 = Pl + 60;

    float R1[9], R2[9], R3[9], R4[9], R5[9], R6[9];
    mat3mul(M0, M1, R1);
    mat3mul(M0, M2, R2);
    mat3mul(R1, M3, R3);
    mat3mul(R2, M4, R4);
    mat3mul(R3, M5, R5);
    mat3mul(R4, M6, R6);

    float p0[3] = {bone[0], bone[1], bone[2]};
    float p1[3], p2[3], p3[3], p4a[3], p5[3], p6[3], p7[3], p8[3];
    mva(M0, bone + 3,  p0, p1);
    mva(M0, bone + 6,  p0, p2);
    mva(R1, bone + 9,  p1, p3);
    mva(R2, bone + 12, p2, p4a);
    mva(R3, bone + 15, p3, p5);
    mva(R4, bone + 18, p4a, p6);
    mva(R5, bone + 21, p5, p7);
    mva(R6, bone + 24, p6, p8);

    // FEET = [7,5,8,6]
    feet[0] = p7[0]; feet[1]  = p7[1]; feet[2]  = p7[2];
    feet[3] = p5[0]; feet[4]  = p5[1]; feet[5]  = p5[2];
    feet[6] = p8[0]; feet[7]  = p8[1]; feet[8]  = p8[2];
    feet[9] = p6[0]; feet[10] = p6[1]; feet[11] = p6[2];
    *fmin = fminf(fminf(p5[1], p6[1]), fminf(p7[1], p8[1]));
}

// FK from transposed compact LDS tile: float f of column c at tile[f*TILE_W+c]
// (stride 65 across lanes -> 2 lanes/bank = conflict-free)
__device__ __forceinline__ void fk_feet_col(const float* __restrict__ tile, int col,
                                            const float* __restrict__ bone,
                                            float feet[12], float* fmin) {
    float Pl[TILE_F];
#pragma unroll
    for (int f = 0; f < TILE_F; ++f) Pl[f] = tile[f * TILE_W + col];
    fk_core(Pl, bone, feet, fmin);
}

// inclusive wave scan (non-commutative compose, earlier = lower lane)
__device__ __forceinline__ void wave_incl_scan(float& Sx, float& Sz,
                                               float& A, float& B, int lane) {
#pragma unroll
    for (int off = 1; off < 64; off <<= 1) {
        float ox = __shfl_up(Sx, off, 64);
        float oz = __shfl_up(Sz, off, 64);
        float oA = __shfl_up(A, off, 64);
        float oB = __shfl_up(B, off, 64);
        if (lane >= off) {
            Sx += ox;
            Sz += oz;
            B = fmaxf(oB + A, B);  // B uses pre-update A
            A = oA + A;
        }
    }
}

// scatter one copied float4 into the transposed compact tile (if needed)
__device__ __forceinline__ void extract_tile(float* __restrict__ tile, int idx, floatx4 q) {
    int tsl = idx / 54;
    int w   = idx - tsl * 54;
    int base = -1;
    if (w <= 6)                  base = 4 * w;       // floats 0..27
    else if (w >= 9 && w <= 13)  base = 4 * w - 8;   // floats 36..55 -> 28..47
    else if (w >= 15 && w <= 20) base = 4 * w - 12;  // floats 60..83 -> 48..71
    if (base >= 0) {
        tile[(base + 0) * TILE_W + tsl] = q.x;
        tile[(base + 1) * TILE_W + tsl] = q.y;
        tile[(base + 2) * TILE_W + tsl] = q.z;
        tile[(base + 3) * TILE_W + tsl] = q.w;
    }
}

// ---------------- main kernel ------------------------------------------------
// Dense copy (round-8 pattern, all loads upfront), boundary f4s loaded by
// tid 128..145 in the same burst, ONE barrier, then wave 0 does FK+scan
// (lane 0 additionally FKs the boundary column). Waves 1-3 exit.

__global__ __launch_bounds__(256) void k_main(const float* __restrict__ pose,
                                              const float* __restrict__ bone,
                                              const int* __restrict__ index,
                                              floatx4* __restrict__ outPose4,
                                              float4* __restrict__ vws,
                                              float4* __restrict__ wsAgg) {
    __shared__ __align__(16) float tile[SCR + 4];
    int tid = threadIdx.x, u = blockIdx.x;

    const floatx4* __restrict__ src = (const floatx4*)pose + (size_t)u * F4PB;
    floatx4*       __restrict__ dst = outPose4              + (size_t)u * F4PB;

    // ---- issue ALL loads up front (dense, coalesced) ----------------------
    floatx4 r[14];
#pragma unroll
    for (int j = 0; j < 13; ++j) r[j] = src[j * 256 + tid];
    floatx4 qb;
    bool has14  = (tid < 128);
    bool hasBnd = (u > 0 && tid >= 128 && tid < 128 + 18);
    if (has14) {
        r[13] = src[13 * 256 + tid];
    } else if (hasBnd) {
        // boundary timestep u*BT-1 (18 needed float4s) -> tile column 64
        int k = tid - 128;
        int o = k + (k >= 7 ? 2 : 0) + (k >= 12 ? 1 : 0);   // {0..6,9..13,15..20}
        qb = *(const floatx4*)(pose + ((size_t)u * BT - 1) * 216 + o * 4);
    }

    // ---- drain: NT store + LDS extract ------------------------------------
#pragma unroll
    for (int j = 0; j < 13; ++j) {
        int idx = j * 256 + tid;
        __builtin_nontemporal_store(r[j], &dst[idx]);
        extract_tile(tile, idx, r[j]);
    }
    if (has14) {
        int idx = 13 * 256 + tid;
        __builtin_nontemporal_store(r[13], &dst[idx]);
        extract_tile(tile, idx, r[13]);
    } else if (hasBnd) {
        int k = tid - 128;
#pragma unroll
        for (int i = 0; i < 4; ++i) tile[(4 * k + i) * TILE_W + 64] = qb[i];
    }
    __syncthreads();

    // ---- wave 0: FK + velocity + inclusive scan ---------------------------
    if (tid < 64) {
        int lane = tid;
        int t = u * BT + lane;

        float feet[12], fmin;
        fk_feet_col(tile, lane, bone, feet, &fmin);

        float fb[12];
        if (lane == 0 && u > 0) {
            float mb;
            fk_feet_col(tile, 64, bone, fb, &mb);   // boundary column
        }

        float fp[12];
#pragma unroll
        for (int k = 0; k < 12; ++k) fp[k] = __shfl_up(feet[k], 1, 64);
        if (lane == 0 && u > 0) {
#pragma unroll
            for (int k = 0; k < 12; ++k) fp[k] = fb[k];
        }

        float vx, vy, vz;
        if (t == 0) {
            vx = 0.f; vy = GRAV_Y; vz = 0.f;
        } else {
            int idx = index[t];
            vx = sel_foot(fp, idx, 0) - sel_foot(feet, idx, 0);
            vy = GRAV_Y + sel_foot(fp, idx, 1) - sel_foot(feet, idx, 1);
            vz = sel_foot(fp, idx, 2) - sel_foot(feet, idx, 2);
        }
        float ix = vx, iz = vz, iA = vy, iB = FLOOR_YC - fmin;
        wave_incl_scan(ix, iz, iA, iB, lane);

        vws[(size_t)t] = make_float4(ix, iz, iA, iB);   // inclusive state
        if (lane == 63) wsAgg[u] = make_float4(ix, iz, iA, iB);
    }
}

// ---------------- apply kernel (folds phase2 + phase3) -----------------------
// Every block redundantly scans the 2048 unit aggregates (32 KB from L2),
// extracts the entering state for its 4 units, and applies to 256 elements.

__global__ __launch_bounds__(256) void k_apply(const float4* __restrict__ wsAgg,
                                               const float4* __restrict__ vws,
                                               float* __restrict__ trans) {
    __shared__ float4 wtot[4];
    __shared__ float4 pre[4];
    int tid = threadIdx.x, bk = blockIdx.x;
    int lane = tid & 63, wv = tid >> 6;

    // thread composes aggregates [tid*8, tid*8+8)
    float4 a[8];
#pragma unroll
    for (int k = 0; k < 8; ++k) a[k] = wsAgg[tid * 8 + k];
    float cx = a[0].x, cz = a[0].y, ca = a[0].z, cb = a[0].w;
#pragma unroll
    for (int k = 1; k < 8; ++k) {
        cb = fmaxf(cb + a[k].z, a[k].w);
        ca += a[k].z;
        cx += a[k].x; cz += a[k].y;
    }

    float sx = cx, sz = cz, sa = ca, sb = cb;
    wave_incl_scan(sx, sz, sa, sb, lane);
    if (lane == 63) wtot[wv] = make_float4(sx, sz, sa, sb);

    // lane-exclusive from inclusive
    float ex = __shfl_up(sx, 1, 64);
    float ez = __shfl_up(sz, 1, 64);
    float eA = __shfl_up(sa, 1, 64);
    float eB = __shfl_up(sb, 1, 64);
    if (lane == 0) { ex = 0.f; ez = 0.f; eA = 0.f; eB = NEG_INF; }
    __syncthreads();

    // wave prefix (earlier waves, composed in order)
    float wx = 0.f, wz = 0.f, wA = 0.f, wB = NEG_INF;
    for (int w = 0; w < wv; ++w) {
        float4 c = wtot[w];
        wx += c.x; wz += c.y;
        wB = fmaxf(wB + c.z, c.w);
        wA += c.z;
    }
    float tx = wx + ex, tz = wz + ez;
    float tB = fmaxf(wB + eA, eB);
    float tA = wA + eA;

    // block bk needs entering states for units bk*4 .. bk*4+3; those agg
    // indices live in thread (bk>>1)'s chunk of 8.
    if (tid == (bk >> 1)) {
        int j0 = bk * 4 - tid * 8;       // 0 or 4
        float px = tx, pz = tz, pA = tA, pB = tB;
#pragma unroll
        for (int k = 0; k < 8; ++k) {
            if (k >= j0 && k < j0 + 4)
                pre[k - j0] = make_float4(px, pz, fmaxf(pA, pB), 0.f);
            pB = fmaxf(pB + a[k].z, a[k].w);
            pA += a[k].z;
            px += a[k].x; pz += a[k].y;
        }
    }
    __syncthreads();

    float4 bin = pre[wv];
    size_t t = ((size_t)bk * 4 + wv) * 64 + lane;
    float4 v = vws[t];
    trans[t * 3 + 0] = bin.x + v.x;
    trans[t * 3 + 1] = fmaxf(bin.z + v.z, v.w);
    trans[t * 3 + 2] = bin.y + v.y;
}

// ---------------- launch -----------------------------------------------------

extern "C" void kernel_launch(void* const* d_in, const int* in_sizes, int n_in,
                              void* d_out, int out_size, void* d_ws, size_t ws_size,
                              hipStream_t stream) {
    const float* pose  = (const float*)d_in[0];
    const float* bone  = (const float*)d_in[1];
    const int*   index = (const int*)d_in[2];
    float* out   = (float*)d_out;
    float* trans = out + POSE_FLTS;

    float4* vws   = (float4*)d_ws;         // T entries (2 MB)
    float4* wsAgg = vws + T_TOTAL;         // NU entries
    (void)ws_size; (void)n_in; (void)in_sizes; (void)out_size;

    k_main <<<NU, 256, 0, stream>>>(pose, bone, index, (floatx4*)out, vws, wsAgg);
    k_apply<<<NU / 4, 256, 0, stream>>>(wsAgg, vws, trans);
}

// Round 11
// 48.770 us; speedup vs baseline: 1.0634x; 1.0197x over previous
//
#include <hip/hip_runtime.h>
#include <math.h>

#define T_TOTAL   131072
#define POSE_FLTS (131072 * 216)       // 28311552
#define BT        64                   // timesteps per scan unit / block
#define NU        (T_TOTAL / BT)       // 2048 units
#define F4PB      (BT * 54)            // 3456 float4 per unit slice
#define TS_STR    73                   // floats per ts in LDS (odd -> 2/bank reads)
#define TILE_F    72                   // compact floats per ts
#define FLOOR_YC  (-0.93f)
#define GRAV_Y    (-0.0018f)
#define NEG_INF   (-INFINITY)

typedef float floatx4 __attribute__((ext_vector_type(4)));

// ---------------- small math helpers (constant-indexed after inlining) ------

__device__ __forceinline__ void mat3mul(const float* A, const float* B, float* C) {
#pragma unroll
    for (int r = 0; r < 3; ++r) {
#pragma unroll
        for (int c = 0; c < 3; ++c) {
            C[r * 3 + c] = fmaf(A[r * 3 + 2], B[6 + c],
                           fmaf(A[r * 3 + 1], B[3 + c],
                                A[r * 3 + 0] * B[c]));
        }
    }
}

__device__ __forceinline__ void mva(const float* R, const float* b,
                                    const float* pin, float* pout) {
#pragma unroll
    for (int r = 0; r < 3; ++r) {
        pout[r] = pin[r] + fmaf(R[r * 3 + 2], b[2],
                            fmaf(R[r * 3 + 1], b[1], R[r * 3 + 0] * b[0]));
    }
}

__device__ __forceinline__ float sel_foot(const float f[12], int idx, int c) {
    float r = f[0 + c];
    r = (idx == 1) ? f[3 + c] : r;
    r = (idx == 2) ? f[6 + c] : r;
    r = (idx == 3) ? f[9 + c] : r;
    return r;
}

// FK core on a compact 72-float pose (joint offsets 0,9,18,28,37,51,60)
__device__ __forceinline__ void fk_core(const float* Pl,
                                        const float* __restrict__ bone,
                                        float feet[12], float* fmin) {
    const float* M0 = Pl + 0;
    const float* M1 = Pl + 9;
    const float* M2 = Pl + 18;
    const float* M3 = Pl + 28;
    const float* M4 = Pl + 37;
    const float* M5 = Pl + 51;
    const float* M6 = Pl + 60;

    float R1[9], R2[9], R3[9], R4[9], R5[9], R6[9];
    mat3mul(M0, M1, R1);
    mat3mul(M0, M2, R2);
    mat3mul(R1, M3, R3);
    mat3mul(R2, M4, R4);
    mat3mul(R3, M5, R5);
    mat3mul(R4, M6, R6);

    float p0[3] = {bone[0], bone[1], bone[2]};
    float p1[3], p2[3], p3[3], p4a[3], p5[3], p6[3], p7[3], p8[3];
    mva(M0, bone + 3,  p0, p1);
    mva(M0, bone + 6,  p0, p2);
    mva(R1, bone + 9,  p1, p3);
    mva(R2, bone + 12, p2, p4a);
    mva(R3, bone + 15, p3, p5);
    mva(R4, bone + 18, p4a, p6);
    mva(R5, bone + 21, p5, p7);
    mva(R6, bone + 24, p6, p8);

    // FEET = [7,5,8,6]
    feet[0] = p7[0]; feet[1]  = p7[1]; feet[2]  = p7[2];
    feet[3] = p5[0]; feet[4]  = p5[1]; feet[5]  = p5[2];
    feet[6] = p8[0]; feet[7]  = p8[1]; feet[8]  = p8[2];
    feet[9] = p6[0]; feet[10] = p6[1]; feet[11] = p6[2];
    *fmin = fminf(fminf(p5[1], p6[1]), fminf(p7[1], p8[1]));
}

// FK from linear compact LDS tile: float f of ts c at tile[c*TS_STR + f].
// reads: bank = (73c + f) mod 32 = (9c + f) mod 32 -> exactly 2 lanes/bank (free)
__device__ __forceinline__ void fk_feet_col(const float* __restrict__ tile, int col,
                                            const float* __restrict__ bone,
                                            float feet[12], float* fmin) {
    float Pl[TILE_F];
    const float* p = tile + col * TS_STR;
#pragma unroll
    for (int f = 0; f < TILE_F; ++f) Pl[f] = p[f];
    fk_core(Pl, bone, feet, fmin);
}

// inclusive wave scan (non-commutative compose, earlier = lower lane)
__device__ __forceinline__ void wave_incl_scan(float& Sx, float& Sz,
                                               float& A, float& B, int lane) {
#pragma unroll
    for (int off = 1; off < 64; off <<= 1) {
        float ox = __shfl_up(Sx, off, 64);
        float oz = __shfl_up(Sz, off, 64);
        float oA = __shfl_up(A, off, 64);
        float oB = __shfl_up(B, off, 64);
        if (lane >= off) {
            Sx += ox;
            Sz += oz;
            B = fmaxf(oB + A, B);  // B uses pre-update A
            A = oA + A;
        }
    }
}

// scatter one copied float4 into the linear compact tile (if needed)
// writes: consecutive active lanes hit consecutive banks (<=3-way)
__device__ __forceinline__ void extract_tile(float* __restrict__ tile, int idx, floatx4 q) {
    int tsl = idx / 54;
    int w   = idx - tsl * 54;
    int base = -1;
    if (w <= 6)                  base = 4 * w;       // floats 0..27
    else if (w >= 9 && w <= 13)  base = 4 * w - 8;   // floats 36..55 -> 28..47
    else if (w >= 15 && w <= 20) base = 4 * w - 12;  // floats 60..83 -> 48..71
    if (base >= 0) {
        float* p = &tile[tsl * TS_STR + base];
        p[0] = q.x; p[1] = q.y; p[2] = q.z; p[3] = q.w;
    }
}

// ---------------- main kernel ------------------------------------------------
// Dense copy (all loads upfront), boundary f4s loaded by tid 128..145 in the
// same burst, ONE barrier, then wave 0 does FK+scan (lane 0 additionally FKs
// the boundary column 64). Waves 1-3 exit after the drain.

__global__ __launch_bounds__(256) void k_main(const float* __restrict__ pose,
                                              const float* __restrict__ bone,
                                              const int* __restrict__ index,
                                              floatx4* __restrict__ outPose4,
                                              float4* __restrict__ vws,
                                              float4* __restrict__ wsAgg) {
    __shared__ __align__(16) float tile[65 * TS_STR + 4];
    int tid = threadIdx.x, u = blockIdx.x;

    const floatx4* __restrict__ src = (const floatx4*)pose + (size_t)u * F4PB;
    floatx4*       __restrict__ dst = outPose4              + (size_t)u * F4PB;

    // ---- issue ALL loads up front (dense, coalesced) ----------------------
    floatx4 r[14];
#pragma unroll
    for (int j = 0; j < 13; ++j) r[j] = src[j * 256 + tid];
    floatx4 qb;
    bool has14  = (tid < 128);
    bool hasBnd = (u > 0 && tid >= 128 && tid < 128 + 18);
    if (has14) {
        r[13] = src[13 * 256 + tid];
    } else if (hasBnd) {
        // boundary timestep u*BT-1 (18 needed float4s) -> tile row 64
        int k = tid - 128;
        int o = k + (k >= 7 ? 2 : 0) + (k >= 12 ? 1 : 0);   // {0..6,9..13,15..20}
        qb = *(const floatx4*)(pose + ((size_t)u * BT - 1) * 216 + o * 4);
    }
    // prefetch this lane's index value (used by wave 0 after the barrier)
    int idxv = 0;
    if (tid < 64) idxv = index[u * BT + tid];

    // ---- drain: NT store + LDS extract ------------------------------------
#pragma unroll
    for (int j = 0; j < 13; ++j) {
        int idx = j * 256 + tid;
        __builtin_nontemporal_store(r[j], &dst[idx]);
        extract_tile(tile, idx, r[j]);
    }
    if (has14) {
        int idx = 13 * 256 + tid;
        __builtin_nontemporal_store(r[13], &dst[idx]);
        extract_tile(tile, idx, r[13]);
    } else if (hasBnd) {
        int k = tid - 128;
        float* p = &tile[64 * TS_STR + 4 * k];
#pragma unroll
        for (int i = 0; i < 4; ++i) p[i] = qb[i];
    }
    __syncthreads();

    // ---- wave 0: FK + velocity + inclusive scan ---------------------------
    if (tid < 64) {
        int lane = tid;
        int t = u * BT + lane;

        float feet[12], fmin;
        fk_feet_col(tile, lane, bone, feet, &fmin);

        float fb[12];
        if (lane == 0 && u > 0) {
            float mb;
            fk_feet_col(tile, 64, bone, fb, &mb);   // boundary column
        }

        float fp[12];
#pragma unroll
        for (int k = 0; k < 12; ++k) fp[k] = __shfl_up(feet[k], 1, 64);
        if (lane == 0 && u > 0) {
#pragma unroll
            for (int k = 0; k < 12; ++k) fp[k] = fb[k];
        }

        float vx, vy, vz;
        if (t == 0) {
            vx = 0.f; vy = GRAV_Y; vz = 0.f;
        } else {
            vx = sel_foot(fp, idxv, 0) - sel_foot(feet, idxv, 0);
            vy = GRAV_Y + sel_foot(fp, idxv, 1) - sel_foot(feet, idxv, 1);
            vz = sel_foot(fp, idxv, 2) - sel_foot(feet, idxv, 2);
        }
        float ix = vx, iz = vz, iA = vy, iB = FLOOR_YC - fmin;
        wave_incl_scan(ix, iz, iA, iB, lane);

        vws[(size_t)t] = make_float4(ix, iz, iA, iB);   // inclusive state
        if (lane == 63) wsAgg[u] = make_float4(ix, iz, iA, iB);
    }
}

// ---------------- apply kernel (folds phase2 + phase3) -----------------------
// Every block redundantly scans the 2048 unit aggregates (32 KB from L2),
// extracts the entering state for its 4 units, and applies to 256 elements.

__global__ __launch_bounds__(256) void k_apply(const float4* __restrict__ wsAgg,
                                               const float4* __restrict__ vws,
                                               float* __restrict__ trans) {
    __shared__ float4 wtot[4];
    __shared__ float4 pre[4];
    int tid = threadIdx.x, bk = blockIdx.x;
    int lane = tid & 63, wv = tid >> 6;

    // thread composes aggregates [tid*8, tid*8+8)
    float4 a[8];
#pragma unroll
    for (int k = 0; k < 8; ++k) a[k] = wsAgg[tid * 8 + k];
    float cx = a[0].x, cz = a[0].y, ca = a[0].z, cb = a[0].w;
#pragma unroll
    for (int k = 1; k < 8; ++k) {
        cb = fmaxf(cb + a[k].z, a[k].w);
        ca += a[k].z;
        cx += a[k].x; cz += a[k].y;
    }

    float sx = cx, sz = cz, sa = ca, sb = cb;
    wave_incl_scan(sx, sz, sa, sb, lane);
    if (lane == 63) wtot[wv] = make_float4(sx, sz, sa, sb);

    // lane-exclusive from inclusive
    float ex = __shfl_up(sx, 1, 64);
    float ez = __shfl_up(sz, 1, 64);
    float eA = __shfl_up(sa, 1, 64);
    float eB = __shfl_up(sb, 1, 64);
    if (lane == 0) { ex = 0.f; ez = 0.f; eA = 0.f; eB = NEG_INF; }
    __syncthreads();

    // wave prefix (earlier waves, composed in order)
    float wx = 0.f, wz = 0.f, wA = 0.f, wB = NEG_INF;
    for (int w = 0; w < wv; ++w) {
        float4 c = wtot[w];
        wx += c.x; wz += c.y;
        wB = fmaxf(wB + c.z, c.w);
        wA += c.z;
    }
    float tx = wx + ex, tz = wz + ez;
    float tB = fmaxf(wB + eA, eB);
    float tA = wA + eA;

    // block bk needs entering states for units bk*4 .. bk*4+3; those agg
    // indices live in thread (bk>>1)'s chunk of 8.
    if (tid == (bk >> 1)) {
        int j0 = bk * 4 - tid * 8;       // 0 or 4
        float px = tx, pz = tz, pA = tA, pB = tB;
#pragma unroll
        for (int k = 0; k < 8; ++k) {
            if (k >= j0 && k < j0 + 4)
                pre[k - j0] = make_float4(px, pz, fmaxf(pA, pB), 0.f);
            pB = fmaxf(pB + a[k].z, a[k].w);
            pA += a[k].z;
            px += a[k].x; pz += a[k].y;
        }
    }
    __syncthreads();

    float4 bin = pre[wv];
    size_t t = ((size_t)bk * 4 + wv) * 64 + lane;
    float4 v = vws[t];
    trans[t * 3 + 0] = bin.x + v.x;
    trans[t * 3 + 1] = fmaxf(bin.z + v.z, v.w);
    trans[t * 3 + 2] = bin.y + v.y;
}

// ---------------- launch -----------------------------------------------------

extern "C" void kernel_launch(void* const* d_in, const int* in_sizes, int n_in,
                              void* d_out, int out_size, void* d_ws, size_t ws_size,
                              hipStream_t stream) {
    const float* pose  = (const float*)d_in[0];
    const float* bone  = (const float*)d_in[1];
    const int*   index = (const int*)d_in[2];
    float* out   = (float*)d_out;
    float* trans = out + POSE_FLTS;

    float4* vws   = (float4*)d_ws;         // T entries (2 MB)
    float4* wsAgg = vws + T_TOTAL;         // NU entries
    (void)ws_size; (void)n_in; (void)in_sizes; (void)out_size;

    k_main <<<NU, 256, 0, stream>>>(pose, bone, index, (floatx4*)out, vws, wsAgg);
    k_apply<<<NU / 4, 256, 0, stream>>>(wsAgg, vws, trans);
}

// Round 12
// 46.311 us; speedup vs baseline: 1.1199x; 1.0531x over previous
//
#include <hip/hip_runtime.h>
#include <math.h>

#define T_TOTAL   131072
#define POSE_FLTS (131072 * 216)       // 28311552
#define BT        64                   // timesteps per scan unit / block
#define NU        (T_TOTAL / BT)       // 2048 units
#define F4PB      (BT * 54)            // 3456 float4 per unit slice
#define FLOOR_YC  (-0.93f)
#define GRAV_Y    (-0.0018f)
#define NEG_INF   (-INFINITY)

typedef float floatx4 __attribute__((ext_vector_type(4)));

// ---------------- small math helpers (constant-indexed after inlining) ------

__device__ __forceinline__ void mat3mul(const float* A, const float* B, float* C) {
#pragma unroll
    for (int r = 0; r < 3; ++r) {
#pragma unroll
        for (int c = 0; c < 3; ++c) {
            C[r * 3 + c] = fmaf(A[r * 3 + 2], B[6 + c],
                           fmaf(A[r * 3 + 1], B[3 + c],
                                A[r * 3 + 0] * B[c]));
        }
    }
}

__device__ __forceinline__ void mva(const float* R, const float* b,
                                    const float* pin, float* pout) {
#pragma unroll
    for (int r = 0; r < 3; ++r) {
        pout[r] = pin[r] + fmaf(R[r * 3 + 2], b[2],
                            fmaf(R[r * 3 + 1], b[1], R[r * 3 + 0] * b[0]));
    }
}

__device__ __forceinline__ float sel_foot(const float f[12], int idx, int c) {
    float r = f[0 + c];
    r = (idx == 1) ? f[3 + c] : r;
    r = (idx == 2) ? f[6 + c] : r;
    r = (idx == 3) ? f[9 + c] : r;
    return r;
}

// FK core on a compact 72-float pose (joint offsets 0,9,18,28,37,51,60)
__device__ __forceinline__ void fk_core(const float* Pl,
                                        const float* __restrict__ bone,
                                        float feet[12], float* fmin) {
    const float* M0 = Pl + 0;
    const float* M1 = Pl + 9;
    const float* M2 = Pl + 18;
    const float* M3 = Pl + 28;
    const float* M4 = Pl + 37;
    const float* M5 = Pl + 51;
    const float* M6 = Pl + 60;

    float R1[9], R2[9], R3[9], R4[9], R5[9], R6[9];
    mat3mul(M0, M1, R1);
    mat3mul(M0, M2, R2);
    mat3mul(R1, M3, R3);
    mat3mul(R2, M4, R4);
    mat3mul(R3, M5, R5);
    mat3mul(R4, M6, R6);

    float p0[3] = {bone[0], bone[1], bone[2]};
    float p1[3], p2[3], p3[3], p4a[3], p5[3], p6[3], p7[3], p8[3];
    mva(M0, bone + 3,  p0, p1);
    mva(M0, bone + 6,  p0, p2);
    mva(R1, bone + 9,  p1, p3);
    mva(R2, bone + 12, p2, p4a);
    mva(R3, bone + 15, p3, p5);
    mva(R4, bone + 18, p4a, p6);
    mva(R5, bone + 21, p5, p7);
    mva(R6, bone + 24, p6, p8);

    // FEET = [7,5,8,6]
    feet[0] = p7[0]; feet[1]  = p7[1]; feet[2]  = p7[2];
    feet[3] = p5[0]; feet[4]  = p5[1]; feet[5]  = p5[2];
    feet[6] = p8[0]; feet[7]  = p8[1]; feet[8]  = p8[2];
    feet[9] = p6[0]; feet[10] = p6[1]; feet[11] = p6[2];
    *fmin = fminf(fminf(p5[1], p6[1]), fminf(p7[1], p8[1]));
}

// load the 18 needed float4s of one timestep into compact Pl[72]
__device__ __forceinline__ void load_compact(const floatx4* __restrict__ pp,
                                             float Pl[72]) {
#pragma unroll
    for (int k = 0; k < 18; ++k) {
        int o = k + (k >= 7 ? 2 : 0) + (k >= 12 ? 1 : 0);   // {0..6,9..13,15..20}
        floatx4 q = pp[o];
        Pl[4 * k + 0] = q.x;
        Pl[4 * k + 1] = q.y;
        Pl[4 * k + 2] = q.z;
        Pl[4 * k + 3] = q.w;
    }
}

// inclusive wave scan (non-commutative compose, earlier = lower lane)
__device__ __forceinline__ void wave_incl_scan(float& Sx, float& Sz,
                                               float& A, float& B, int lane) {
#pragma unroll
    for (int off = 1; off < 64; off <<= 1) {
        float ox = __shfl_up(Sx, off, 64);
        float oz = __shfl_up(Sz, off, 64);
        float oA = __shfl_up(A, off, 64);
        float oB = __shfl_up(B, off, 64);
        if (lane >= off) {
            Sx += ox;
            Sz += oz;
            B = fmaxf(oB + A, B);  // B uses pre-update A
            A = oA + A;
        }
    }
}

// ---------------- main kernel ------------------------------------------------
// Barrier-free: waves 1-3 stream the 64-ts slice (pure copy, no LDS); wave 0
// reads its own FK data from global (L2-hot from the same block's copy),
// FKs the boundary ts on all lanes (uniform loads), scans, writes vws/agg.

__global__ __launch_bounds__(256) void k_main(const float* __restrict__ pose,
                                              const float* __restrict__ bone,
                                              const int* __restrict__ index,
                                              floatx4* __restrict__ outPose4,
                                              float4* __restrict__ vws,
                                              float4* __restrict__ wsAgg) {
    int tid = threadIdx.x, u = blockIdx.x;

    if (tid >= 64) {
        // ---- copy role: 18 f4 per thread, 2 batches of 9 ------------------
        int tt = tid - 64;                    // 0..191
        const floatx4* __restrict__ src = (const floatx4*)pose + (size_t)u * F4PB;
        floatx4*       __restrict__ dst = outPose4              + (size_t)u * F4PB;
#pragma unroll
        for (int bat = 0; bat < 2; ++bat) {
            floatx4 r[9];
#pragma unroll
            for (int j = 0; j < 9; ++j)
                r[j] = src[(bat * 9 + j) * 192 + tt];
#pragma unroll
            for (int j = 0; j < 9; ++j)
                __builtin_nontemporal_store(r[j], &dst[(bat * 9 + j) * 192 + tt]);
        }
        return;
    }

    // ---- wave 0: FK + velocity + inclusive scan ---------------------------
    int lane = tid;
    int t = u * BT + lane;
    int idxv = index[t];

    // issue own-ts loads first (latency hides under boundary FK)
    float Pl[72];
    load_compact((const floatx4*)(pose + (size_t)t * 216), Pl);

    // boundary ts (u*BT-1): lane-uniform loads, FK on all lanes (no divergence)
    float fb[12];
    if (u > 0) {
        float Pb[72], mb;
        load_compact((const floatx4*)(pose + ((size_t)u * BT - 1) * 216), Pb);
        fk_core(Pb, bone, fb, &mb);
    }

    float feet[12], fmin;
    fk_core(Pl, bone, feet, &fmin);

    float fp[12];
#pragma unroll
    for (int k = 0; k < 12; ++k) fp[k] = __shfl_up(feet[k], 1, 64);
    if (lane == 0 && u > 0) {
#pragma unroll
        for (int k = 0; k < 12; ++k) fp[k] = fb[k];
    }

    float vx, vy, vz;
    if (t == 0) {
        vx = 0.f; vy = GRAV_Y; vz = 0.f;
    } else {
        vx = sel_foot(fp, idxv, 0) - sel_foot(feet, idxv, 0);
        vy = GRAV_Y + sel_foot(fp, idxv, 1) - sel_foot(feet, idxv, 1);
        vz = sel_foot(fp, idxv, 2) - sel_foot(feet, idxv, 2);
    }
    float ix = vx, iz = vz, iA = vy, iB = FLOOR_YC - fmin;
    wave_incl_scan(ix, iz, iA, iB, lane);

    vws[(size_t)t] = make_float4(ix, iz, iA, iB);       // inclusive state
    if (lane == 63) wsAgg[u] = make_float4(ix, iz, iA, iB);
}

// ---------------- apply kernel (folds phase2 + phase3) -----------------------
// Every block redundantly scans the 2048 unit aggregates (32 KB from L2),
// extracts the entering state for its 4 units, and applies to 256 elements.

__global__ __launch_bounds__(256) void k_apply(const float4* __restrict__ wsAgg,
                                               const float4* __restrict__ vws,
                                               float* __restrict__ trans) {
    __shared__ float4 wtot[4];
    __shared__ float4 pre[4];
    int tid = threadIdx.x, bk = blockIdx.x;
    int lane = tid & 63, wv = tid >> 6;

    // thread composes aggregates [tid*8, tid*8+8)
    float4 a[8];
#pragma unroll
    for (int k = 0; k < 8; ++k) a[k] = wsAgg[tid * 8 + k];
    float cx = a[0].x, cz = a[0].y, ca = a[0].z, cb = a[0].w;
#pragma unroll
    for (int k = 1; k < 8; ++k) {
        cb = fmaxf(cb + a[k].z, a[k].w);
        ca += a[k].z;
        cx += a[k].x; cz += a[k].y;
    }

    float sx = cx, sz = cz, sa = ca, sb = cb;
    wave_incl_scan(sx, sz, sa, sb, lane);
    if (lane == 63) wtot[wv] = make_float4(sx, sz, sa, sb);

    // lane-exclusive from inclusive
    float ex = __shfl_up(sx, 1, 64);
    float ez = __shfl_up(sz, 1, 64);
    float eA = __shfl_up(sa, 1, 64);
    float eB = __shfl_up(sb, 1, 64);
    if (lane == 0) { ex = 0.f; ez = 0.f; eA = 0.f; eB = NEG_INF; }
    __syncthreads();

    // wave prefix (earlier waves, composed in order)
    float wx = 0.f, wz = 0.f, wA = 0.f, wB = NEG_INF;
    for (int w = 0; w < wv; ++w) {
        float4 c = wtot[w];
        wx += c.x; wz += c.y;
        wB = fmaxf(wB + c.z, c.w);
        wA += c.z;
    }
    float tx = wx + ex, tz = wz + ez;
    float tB = fmaxf(wB + eA, eB);
    float tA = wA + eA;

    // block bk needs entering states for units bk*4 .. bk*4+3; those agg
    // indices live in thread (bk>>1)'s chunk of 8.
    if (tid == (bk >> 1)) {
        int j0 = bk * 4 - tid * 8;       // 0 or 4
        float px = tx, pz = tz, pA = tA, pB = tB;
#pragma unroll
        for (int k = 0; k < 8; ++k) {
            if (k >= j0 && k < j0 + 4)
                pre[k - j0] = make_float4(px, pz, fmaxf(pA, pB), 0.f);
            pB = fmaxf(pB + a[k].z, a[k].w);
            pA += a[k].z;
            px += a[k].x; pz += a[k].y;
        }
    }
    __syncthreads();

    float4 bin = pre[wv];
    size_t t = ((size_t)bk * 4 + wv) * 64 + lane;
    float4 v = vws[t];
    trans[t * 3 + 0] = bin.x + v.x;
    trans[t * 3 + 1] = fmaxf(bin.z + v.z, v.w);
    trans[t * 3 + 2] = bin.y + v.y;
}

// ---------------- launch -----------------------------------------------------

extern "C" void kernel_launch(void* const* d_in, const int* in_sizes, int n_in,
                              void* d_out, int out_size, void* d_ws, size_t ws_size,
                              hipStream_t stream) {
    const float* pose  = (const float*)d_in[0];
    const float* bone  = (const float*)d_in[1];
    const int*   index = (const int*)d_in[2];
    float* out   = (float*)d_out;
    float* trans = out + POSE_FLTS;

    float4* vws   = (float4*)d_ws;         // T entries (2 MB)
    float4* wsAgg = vws + T_TOTAL;         // NU entries
    (void)ws_size; (void)n_in; (void)in_sizes; (void)out_size;

    k_main <<<NU, 256, 0, stream>>>(pose, bone, index, (floatx4*)out, vws, wsAgg);
    k_apply<<<NU / 4, 256, 0, stream>>>(wsAgg, vws, trans);
}